// Round 1
// baseline (738.858 us; speedup 1.0000x reference)
//
#include <hip/hip_runtime.h>
#include <math.h>

#define BB 16
#define CC 128
#define HH 224
#define WW 224
#define HW (HH * WW)            // 50176
#define CHW (CC * HW)           // 6422528
#define TOTAL (BB * CHW)        // 102760448

// Kernel 1: channel pool (max + mean over C) -> pooled [B, 2, H, W]
// One thread per 4 consecutive spatial positions (float4).
__global__ void pool_kernel(const float* __restrict__ x, float* __restrict__ pooled) {
    int tid = blockIdx.x * blockDim.x + threadIdx.x;      // [0, B*HW/4)
    int b = tid / (HW / 4);
    int r = (tid - b * (HW / 4)) * 4;                     // spatial offset within image
    const float4* xp = (const float4*)(x + (size_t)b * CHW + r);
    float4 v = xp[0];
    float4 mx = v;
    float4 sm = v;
    #pragma unroll 4
    for (int c = 1; c < CC; ++c) {
        v = xp[(size_t)c * (HW / 4)];
        mx.x = fmaxf(mx.x, v.x); mx.y = fmaxf(mx.y, v.y);
        mx.z = fmaxf(mx.z, v.z); mx.w = fmaxf(mx.w, v.w);
        sm.x += v.x; sm.y += v.y; sm.z += v.z; sm.w += v.w;
    }
    const float inv = 1.0f / (float)CC;
    sm.x *= inv; sm.y *= inv; sm.z *= inv; sm.w *= inv;
    float* base = pooled + (size_t)b * 2 * HW + r;
    *(float4*)(base) = mx;            // channel 0: max
    *(float4*)(base + HW) = sm;       // channel 1: mean
}

// Kernel 2: 3x3 conv (2->1 ch, pad 1) + bias + sigmoid -> scale [B, H, W]
__global__ void conv_kernel(const float* __restrict__ pooled,
                            const float* __restrict__ cw,
                            const float* __restrict__ cb,
                            float* __restrict__ scale) {
    int tid = blockIdx.x * blockDim.x + threadIdx.x;      // [0, B*HW)
    int b = tid / HW;
    int hw = tid - b * HW;
    int h = hw / WW;
    int w = hw - h * WW;
    float acc = cb[0];
    #pragma unroll
    for (int ic = 0; ic < 2; ++ic) {
        const float* pp = pooled + (size_t)b * 2 * HW + (size_t)ic * HW;
        #pragma unroll
        for (int kh = 0; kh < 3; ++kh) {
            int hh = h + kh - 1;
            if (hh < 0 || hh >= HH) continue;
            #pragma unroll
            for (int kw = 0; kw < 3; ++kw) {
                int ww2 = w + kw - 1;
                if (ww2 < 0 || ww2 >= WW) continue;
                acc += pp[hh * WW + ww2] * cw[ic * 9 + kh * 3 + kw];
            }
        }
    }
    scale[tid] = 1.0f / (1.0f + __expf(-acc));
}

// Kernel 3: out = x * scale (broadcast over C), float4 vectorized.
__global__ void mult_kernel(const float* __restrict__ x,
                            const float* __restrict__ scale,
                            float* __restrict__ out) {
    int tid = blockIdx.x * blockDim.x + threadIdx.x;      // [0, TOTAL/4)
    size_t e = (size_t)tid * 4;
    int b = (int)(e / CHW);
    int rem = (int)(e - (size_t)b * CHW);
    int hw = rem % HW;                                     // multiple of 4
    float4 xv = *(const float4*)(x + e);
    float4 sv = *(const float4*)(scale + (size_t)b * HW + hw);
    float4 ov;
    ov.x = xv.x * sv.x; ov.y = xv.y * sv.y;
    ov.z = xv.z * sv.z; ov.w = xv.w * sv.w;
    *(float4*)(out + e) = ov;
}

extern "C" void kernel_launch(void* const* d_in, const int* in_sizes, int n_in,
                              void* d_out, int out_size, void* d_ws, size_t ws_size,
                              hipStream_t stream) {
    const float* x  = (const float*)d_in[0];
    const float* cw = (const float*)d_in[1];   // [1,2,3,3] = 18 floats
    const float* cb = (const float*)d_in[2];   // [1]
    float* out = (float*)d_out;

    float* pooled = (float*)d_ws;                          // B*2*HW = 1605632 floats
    float* scale  = pooled + (size_t)BB * 2 * HW;          // B*HW   =  802816 floats

    // Kernel 1: B*HW/4 = 200704 threads
    pool_kernel<<<(BB * HW / 4) / 256, 256, 0, stream>>>(x, pooled);
    // Kernel 2: B*HW = 802816 threads
    conv_kernel<<<(BB * HW) / 256, 256, 0, stream>>>(pooled, cw, cb, scale);
    // Kernel 3: TOTAL/4 = 25690112 threads
    mult_kernel<<<(TOTAL / 4) / 256, 256, 0, stream>>>(x, scale, out);
}